// Round 1
// baseline (162.006 us; speedup 1.0000x reference)
//
#include <hip/hip_runtime.h>

// 5x5 median blur, zero padding, float32, exact (median = 13th of 25).
// Forgetful selection: min/max of any 14-subset of 25 cannot be the median.

#define S2(a, b) { float _mn = fminf(a, b); (b) = fmaxf(a, b); (a) = _mn; }

// minmax over s0..s13: after this, s0 = min of all 14, s13 = max of all 14,
// middle 12 values (s1..s12) are the remaining multiset in arbitrary order.
#define MINMAX14 \
  S2(s0, s7) S2(s1, s8) S2(s2, s9) S2(s3, s10) S2(s4, s11) S2(s5, s12) S2(s6, s13) \
  S2(s0, s1) S2(s0, s2) S2(s0, s3) S2(s0, s4) S2(s0, s5) S2(s0, s6) \
  S2(s7, s13) S2(s8, s13) S2(s9, s13) S2(s10, s13) S2(s11, s13) S2(s12, s13)

#define TILE_W 36   // 32 + 4 halo
#define TILE_H 12   // 8 + 4 halo

__global__ __launch_bounds__(256) void median5x5_kernel(
    const float* __restrict__ in, float* __restrict__ out, int H, int W)
{
    const int tx = threadIdx.x;           // 0..31
    const int ty = threadIdx.y;           // 0..7
    const int ch = blockIdx.z;

    __shared__ float tile[TILE_H][TILE_W];

    const float* img = in + (size_t)ch * H * W;
    const int bx0 = blockIdx.x * 32 - 2;  // global x of tile col 0
    const int by0 = blockIdx.y * 8 - 2;   // global y of tile row 0

    // Cooperative load, zero-fill out-of-bounds (matches zero padding).
    for (int gy = ty; gy < TILE_H; gy += 8) {
        const int iy = by0 + gy;
        const bool yok = (iy >= 0) && (iy < H);
        const size_t rowbase = (size_t)iy * W;
        for (int gx = tx; gx < TILE_W; gx += 32) {
            const int ix = bx0 + gx;
            float v = 0.0f;
            if (yok && ix >= 0 && ix < W) v = img[rowbase + ix];
            tile[gy][gx] = v;
        }
    }
    __syncthreads();

    // Window value k (row-major in the 5x5 window), k = 0..24
#define V(k) tile[ty + (k) / 5][tx + (k) % 5]

    float s0 = V(0),  s1 = V(1),  s2 = V(2),  s3 = V(3),  s4 = V(4);
    float s5 = V(5),  s6 = V(6),  s7 = V(7),  s8 = V(8),  s9 = V(9);
    float s10 = V(10), s11 = V(11), s12 = V(12), s13 = V(13);

    // Forgetful phase: discard min+max of the 14 in hand, refill with 2 new.
    MINMAX14; s0 = V(14); s13 = V(15);
    MINMAX14; s0 = V(16); s13 = V(17);
    MINMAX14; s0 = V(18); s13 = V(19);
    MINMAX14; s0 = V(20); s13 = V(21);
    MINMAX14; s0 = V(22); s13 = V(23);
    MINMAX14; s0 = V(24);
    // 13 valid elements now: s0..s12. Median of original = 7th of these 13.

    // minmax13 over s0..s12 -> discard s0 (min), s12 (max); valid s1..s11
    S2(s0, s7) S2(s1, s8) S2(s2, s9) S2(s3, s10) S2(s4, s11) S2(s5, s12)
    S2(s0, s1) S2(s0, s2) S2(s0, s3) S2(s0, s4) S2(s0, s5) S2(s0, s6)
    S2(s7, s12) S2(s8, s12) S2(s9, s12) S2(s10, s12) S2(s11, s12) S2(s6, s12)

    // minmax11 over s1..s11 -> valid s2..s10
    S2(s1, s7) S2(s2, s8) S2(s3, s9) S2(s4, s10) S2(s5, s11)
    S2(s1, s2) S2(s1, s3) S2(s1, s4) S2(s1, s5) S2(s1, s6)
    S2(s7, s11) S2(s8, s11) S2(s9, s11) S2(s10, s11) S2(s6, s11)

    // minmax9 over s2..s10 -> valid s3..s9
    S2(s2, s7) S2(s3, s8) S2(s4, s9) S2(s5, s10)
    S2(s2, s3) S2(s2, s4) S2(s2, s5) S2(s2, s6)
    S2(s7, s10) S2(s8, s10) S2(s9, s10) S2(s6, s10)

    // minmax7 over s3..s9 -> valid s4..s8
    S2(s3, s7) S2(s4, s8) S2(s5, s9)
    S2(s3, s4) S2(s3, s5) S2(s3, s6)
    S2(s7, s9) S2(s8, s9) S2(s6, s9)

    // minmax5 over s4..s8 -> valid s5..s7
    S2(s4, s7) S2(s5, s8)
    S2(s4, s5) S2(s4, s6)
    S2(s7, s8) S2(s6, s8)

    // median of 3: s5, s6, s7
    const float mn = fminf(s5, s6);
    const float mx = fmaxf(s5, s6);
    const float med = fmaxf(mn, fminf(mx, s7));

    const int ox = blockIdx.x * 32 + tx;
    const int oy = blockIdx.y * 8 + ty;
    if (ox < W && oy < H) {
        out[(size_t)ch * H * W + (size_t)oy * W + ox] = med;
    }
#undef V
}

extern "C" void kernel_launch(void* const* d_in, const int* in_sizes, int n_in,
                              void* d_out, int out_size, void* d_ws, size_t ws_size,
                              hipStream_t stream) {
    const float* x = (const float*)d_in[0];
    float* out = (float*)d_out;
    const int H = 1024, W = 1024;
    const int nch = in_sizes[0] / (H * W);   // B*C = 12

    dim3 block(32, 8, 1);
    dim3 grid(W / 32, H / 8, nch);
    median5x5_kernel<<<grid, block, 0, stream>>>(x, out, H, W);
}

// Round 2
// 86.523 us; speedup vs baseline: 1.8724x; 1.8724x over previous
//
#include <hip/hip_runtime.h>

// 5x5 median blur, zero padding, float32, exact (lower median = 13th of 25).
// 2 vertical outputs per thread; forgetful selection with shared 20-element
// intersection phase + shrinking working sets + v_med3_f32 finish.

#define S2(a, b) { float _t = fminf(a, b); (b) = fmaxf(a, b); (a) = _t; }

// minmax over s[0..W-1]: s[0] = min, s[W-1] = max, s[1..W-2] = remaining
// multiset (order arbitrary). Fully unrolled, compile-time indices only.
template<int W>
__device__ __forceinline__ void mm(float* s) {
    constexpr int h = W / 2;
#pragma unroll
    for (int i = 0; i < h; ++i) S2(s[i], s[i + h]);
#pragma unroll
    for (int i = 1; i < h; ++i) S2(s[0], s[i]);
    if constexpr (W & 1) S2(s[0], s[W - 1]);   // loose element joins min side
#pragma unroll
    for (int i = h; i < W - 1; ++i) S2(s[i], s[W - 1]);
}

// m[0..8]: 9 shared survivors; pool3[0..2]: untouched shared; priv5: 5 private.
// Live = 17, need 9th smallest (d=4 pair-discards already applied).
__device__ __forceinline__ float phase2(const float* m, const float* pool3,
                                        const float* priv5) {
    float s[10];
    s[0] = priv5[0];
#pragma unroll
    for (int i = 0; i < 9; ++i) s[i + 1] = m[i];
    float p0 = pool3[0], p1 = pool3[1], p2 = pool3[2];
    float p3 = priv5[1], p4 = priv5[2], p5 = priv5[3], p6 = priv5[4];
    mm<10>(s); s[0] = p0;   // d=4
    mm<9>(s);  s[0] = p1;   // d=5
    mm<8>(s);  s[0] = p2;   // d=6
    mm<7>(s);  s[0] = p3;   // d=7
    mm<6>(s);  s[0] = p4;   // d=8
    mm<5>(s);  s[0] = p5;   // d=9
    mm<4>(s);  s[0] = p6;   // d=10 -> live 3, k'=2
    return __builtin_amdgcn_fmed3f(s[0], s[1], s[2]);
}

#define TILE_W 36   // 32 + 4 halo
#define TILE_H 20   // 16 + 4 halo

__global__ __launch_bounds__(256) void median5x5_kernel(
    const float* __restrict__ in, float* __restrict__ out, int H, int W)
{
    const int tx = threadIdx.x;            // 0..31
    const int ty = threadIdx.y;            // 0..7
    const int ch = blockIdx.z;

    __shared__ float tile[TILE_H][TILE_W];

    const float* img = in + (size_t)ch * H * W;
    const int bx0 = blockIdx.x * 32 - 2;   // global x of tile col 0
    const int by0 = blockIdx.y * 16 - 2;   // global y of tile row 0

    // Cooperative staging, zero-fill OOB (matches zero padding).
    const int tid = ty * 32 + tx;
    for (int i = tid; i < TILE_H * TILE_W; i += 256) {
        const int gy = i / TILE_W, gx = i - gy * TILE_W;
        const int iy = by0 + gy, ix = bx0 + gx;
        float v = 0.0f;
        if (iy >= 0 && iy < H && ix >= 0 && ix < W) v = img[(size_t)iy * W + ix];
        tile[gy][gx] = v;
    }
    __syncthreads();

    // Thread handles output rows (2*ty, 2*ty+1) of the block, col tx.
    // Window A (top output): tile rows 2ty+0 .. 2ty+4
    // Window B (bottom):     tile rows 2ty+1 .. 2ty+5
    // Shared rows: 2ty+1 .. 2ty+4 (20 elements); private rows 2ty, 2ty+5.
    const int r0 = 2 * ty;

    float sh[20];
#pragma unroll
    for (int r = 0; r < 4; ++r)
#pragma unroll
        for (int c = 0; c < 5; ++c)
            sh[r * 5 + c] = tile[r0 + 1 + r][tx + c];

    float privA[5], privB[5];
#pragma unroll
    for (int c = 0; c < 5; ++c) {
        privA[c] = tile[r0][tx + c];
        privB[c] = tile[r0 + 5][tx + c];
    }

    // Shared forgetful phase: 4 pair-discards valid for BOTH windows.
    float s[14];
#pragma unroll
    for (int i = 0; i < 14; ++i) s[i] = sh[i];
    mm<14>(s); s[0] = sh[14];   // d=0
    mm<13>(s); s[0] = sh[15];   // d=1
    mm<12>(s); s[0] = sh[16];   // d=2
    mm<11>(s);                  // d=3 -> mids s[1..9], pool sh[17..19]
    float pool3[3] = { sh[17], sh[18], sh[19] };

    const float medA = phase2(&s[1], pool3, privA);
    const float medB = phase2(&s[1], pool3, privB);

    const int ox = blockIdx.x * 32 + tx;
    const int oy = blockIdx.y * 16 + r0;
    float* op = out + (size_t)ch * H * W + (size_t)oy * W + ox;
    op[0] = medA;
    op[W] = medB;
}

extern "C" void kernel_launch(void* const* d_in, const int* in_sizes, int n_in,
                              void* d_out, int out_size, void* d_ws, size_t ws_size,
                              hipStream_t stream) {
    const float* x = (const float*)d_in[0];
    float* out = (float*)d_out;
    const int H = 1024, W = 1024;
    const int nch = in_sizes[0] / (H * W);   // B*C = 12

    dim3 block(32, 8, 1);
    dim3 grid(W / 32, H / 16, nch);
    median5x5_kernel<<<grid, block, 0, stream>>>(x, out, H, W);
}

// Round 3
// 64.296 us; speedup vs baseline: 2.5197x; 1.3457x over previous
//
#include <hip/hip_runtime.h>

// 5x5 median blur, zero padding, float32, exact (lower median = 13th of 25).
// 2x2 output quad per thread: Batcher-sort the 4x4 shared intersection (16),
// free forgetful drops on the sorted run, then per-window oblivious
// insertion-and-drop of the 9 private elements. All order-statistic based
// (tie-safe, exact).

#define S2(a, b) { float _t = fminf(a, b); (b) = fmaxf(a, b); (a) = _t; }

// Batcher odd-even mergesort (N power of two), compile-time indices.
template<int LO, int N, int R>
__device__ __forceinline__ void oemerge(float* a) {
    constexpr int M = R * 2;
    if constexpr (M < N) {
        oemerge<LO, N, M>(a);
        oemerge<LO + R, N, M>(a);
#pragma unroll
        for (int i = LO + R; i + R < LO + N; i += M) S2(a[i], a[i + R]);
    } else {
        S2(a[LO], a[LO + R]);
    }
}
template<int LO, int N>
__device__ __forceinline__ void oesort(float* a) {
    if constexpr (N > 1) {
        oesort<LO, N / 2>(a);
        oesort<LO + N / 2, N / 2>(a);
        oemerge<LO, N, 1>(a);
    }
}

// s[0..M-1] sorted ascending. Merge t in (M+1 run), drop both ends.
// Result: s[0..M-2] sorted ascending. Dead end-values are DCE'd.
template<int M>
__device__ __forceinline__ void insert_drop(float* s, float t) {
    float carry = t;
    float hi[M];
#pragma unroll
    for (int i = M - 1; i >= 0; --i) {
        hi[i] = fmaxf(s[i], carry);
        carry = fminf(s[i], carry);
    }
#pragma unroll
    for (int i = 0; i + 1 < M; ++i) s[i] = hi[i];
}

// mid10: sorted 10 shared survivors (n=19, k=10 per window); p[9]: privates.
__device__ __forceinline__ float window_median(const float* mid10, const float* p) {
    float w[10];
#pragma unroll
    for (int i = 0; i < 10; ++i) w[i] = mid10[i];
    insert_drop<10>(w, p[0]);   // n=19,k=10: run 11 >= 11 ok -> 9
    insert_drop<9>(w, p[1]);    // n=17,k=9 : run 10 >= 10 ok -> 8
    insert_drop<8>(w, p[2]);    // n=15,k=8 : run 9  >= 9  ok -> 7
    insert_drop<7>(w, p[3]);    // n=13,k=7 : run 8  >= 8  ok -> 6
    insert_drop<6>(w, p[4]);    // n=11,k=6 : run 7  >= 7  ok -> 5
    insert_drop<5>(w, p[5]);    // n=9, k=5 : run 6  >= 6  ok -> 4
    insert_drop<4>(w, p[6]);    // n=7, k=4 : run 5  >= 5  ok -> 3
    // n=5, k=3: median of { sorted w[0..2], p7, p8 }
    const float a = fminf(p[7], p[8]);
    const float b = fmaxf(p[7], p[8]);
    const float lo = fmaxf(w[0], a);
    const float hi = fminf(w[2], b);
    return __builtin_amdgcn_fmed3f(w[1], lo, hi);
}

#define TILE_W 68   // 64 + 4 halo
#define TILE_H 20   // 16 + 4 halo

__global__ __launch_bounds__(256) void median5x5_kernel(
    const float* __restrict__ in, float* __restrict__ out, int H, int W)
{
    const int tx = threadIdx.x;            // 0..31
    const int ty = threadIdx.y;            // 0..7
    const int ch = blockIdx.z;

    __shared__ float tile[TILE_H][TILE_W];

    const float* img = in + (size_t)ch * H * W;
    const int bx0 = blockIdx.x * 64 - 2;   // global x of tile col 0
    const int by0 = blockIdx.y * 16 - 2;   // global y of tile row 0
    const int tid = ty * 32 + tx;

    const bool interior = (bx0 >= 0) && (by0 >= 0) &&
                          (bx0 + TILE_W <= W) && (by0 + TILE_H <= H);
    if (interior) {
        for (int i = tid; i < TILE_H * TILE_W; i += 256) {
            const int gy = i / TILE_W, gx = i - gy * TILE_W;
            tile[gy][gx] = img[(size_t)(by0 + gy) * W + (bx0 + gx)];
        }
    } else {
        for (int i = tid; i < TILE_H * TILE_W; i += 256) {
            const int gy = i / TILE_W, gx = i - gy * TILE_W;
            const int iy = by0 + gy, ix = bx0 + gx;
            float v = 0.0f;
            if (iy >= 0 && iy < H && ix >= 0 && ix < W)
                v = img[(size_t)iy * W + ix];
            tile[gy][gx] = v;
        }
    }
    __syncthreads();

    // Thread's 6x6 neighborhood: tile rows 2ty..2ty+5, cols 2tx..2tx+5.
    float v[6][6];
#pragma unroll
    for (int r = 0; r < 6; ++r)
#pragma unroll
        for (int c = 0; c < 6; ++c)
            v[r][c] = tile[2 * ty + r][2 * tx + c];

    // Shared 4x4 intersection of all four windows: v[1..4][1..4].
    float a[16];
#pragma unroll
    for (int r = 0; r < 4; ++r)
#pragma unroll
        for (int c = 0; c < 4; ++c)
            a[r * 4 + c] = v[r + 1][c + 1];
    oesort<0, 16>(a);
    // Free forgetful drops on sorted 16: n=25,k=13 needs 14 (16 ok);
    // n=23,k=12 needs 13 (14 ok); n=21,k=11 needs 12 (12 ok).
    // Survivors: a[3..12] sorted, n=19, k=10.

    float med[2][2];
#pragma unroll
    for (int wy = 0; wy < 2; ++wy) {
#pragma unroll
        for (int wx = 0; wx < 2; ++wx) {
            // Window (wy,wx): tile rows wy..wy+4, cols wx..wx+4 of v.
            // Privates: row (wy?5:0) cols wx..wx+4, plus col (wx?5:0) rows 1..4.
            float p[9];
            const int pr = wy ? 5 : 0;
            const int pc = wx ? 5 : 0;
#pragma unroll
            for (int c = 0; c < 5; ++c) p[c] = v[pr][wx + c];
#pragma unroll
            for (int r = 0; r < 4; ++r) p[5 + r] = v[r + 1][pc];
            med[wy][wx] = window_median(&a[3], p);
        }
    }

    const int ox = blockIdx.x * 64 + 2 * tx;
    const int oy = blockIdx.y * 16 + 2 * ty;
    float* op = out + (size_t)ch * H * W + (size_t)oy * W + ox;
    *reinterpret_cast<float2*>(op)     = make_float2(med[0][0], med[0][1]);
    *reinterpret_cast<float2*>(op + W) = make_float2(med[1][0], med[1][1]);
}

extern "C" void kernel_launch(void* const* d_in, const int* in_sizes, int n_in,
                              void* d_out, int out_size, void* d_ws, size_t ws_size,
                              hipStream_t stream) {
    const float* x = (const float*)d_in[0];
    float* out = (float*)d_out;
    const int H = 1024, W = 1024;
    const int nch = in_sizes[0] / (H * W);   // B*C = 12

    dim3 block(32, 8, 1);
    dim3 grid(W / 64, H / 16, nch);
    median5x5_kernel<<<grid, block, 0, stream>>>(x, out, H, W);
}

// Round 4
// 53.475 us; speedup vs baseline: 3.0296x; 1.2024x over previous
//
#include <hip/hip_runtime.h>

// 5x5 median blur, zero padding, float32, exact (lower median = 13th of 25).
// 2x2 quad per thread. Batcher-sort the 4x4 shared core (16) -> sorted mids
// S10 (3 forgetful pair-drops are free on a sorted run). Sort the 4 shared
// edge runs (4 each). Per window: Batcher-merge row4+col4 -> M8, then take
// the 10th-smallest of S10 u M8 u {corner} via the sorted-runs selection
// identity: kth = min over i+j+m=k of max(A[i-1], B[j-1], c). Tie-safe, exact.

#define S2(a, b) { float _t = fminf(a, b); (b) = fmaxf(a, b); (a) = _t; }

// Batcher odd-even merge/sort (compile-time indices). oemerge<LO,N,1> merges
// two sorted halves [LO..LO+N/2), [LO+N/2..LO+N).
template<int LO, int N, int R>
__device__ __forceinline__ void oemerge(float* a) {
    constexpr int M = R * 2;
    if constexpr (M < N) {
        oemerge<LO, N, M>(a);
        oemerge<LO + R, N, M>(a);
#pragma unroll
        for (int i = LO + R; i + R < LO + N; i += M) S2(a[i], a[i + R]);
    } else {
        S2(a[LO], a[LO + R]);
    }
}
template<int LO, int N>
__device__ __forceinline__ void oesort(float* a) {
    if constexpr (N > 1) {
        oesort<LO, N / 2>(a);
        oesort<LO + N / 2, N / 2>(a);
        oemerge<LO, N, 1>(a);
    }
}

__device__ __forceinline__ float min3f(float a, float b, float c) {
    return fminf(fminf(a, b), c);   // fuses to v_min3_f32
}

#define TILE_W2 34   // 68 floats = 64 + 4 halo
#define TILE_H  20   // 16 + 4 halo

__global__ __launch_bounds__(256) void median5x5_kernel(
    const float* __restrict__ in, float* __restrict__ out, int H, int W)
{
    const int tx = threadIdx.x;            // 0..31
    const int ty = threadIdx.y;            // 0..7
    const int ch = blockIdx.z;

    __shared__ float2 tile[TILE_H][TILE_W2];

    const float* img = in + (size_t)ch * H * W;
    const int bx0 = blockIdx.x * 64 - 2;   // global x of tile col 0 (even)
    const int by0 = blockIdx.y * 16 - 2;   // global y of tile row 0
    const int tid = ty * 32 + tx;

    const bool interior = (bx0 >= 0) && (by0 >= 0) &&
                          (bx0 + 68 <= W) && (by0 + TILE_H <= H);
    if (interior) {
#pragma unroll
        for (int i = tid; i < TILE_H * TILE_W2; i += 256) {
            const int gy = i / TILE_W2, gx = i - gy * TILE_W2;
            tile[gy][gx] = *((const float2*)(img + (size_t)(by0 + gy) * W + bx0) + gx);
        }
    } else {
        float* tf = (float*)tile;          // same row-major [20][68] layout
        for (int i = tid; i < TILE_H * 68; i += 256) {
            const int gy = i / 68, gx = i - gy * 68;
            const int iy = by0 + gy, ix = bx0 + gx;
            float u = 0.0f;
            if (iy >= 0 && iy < H && ix >= 0 && ix < W)
                u = img[(size_t)iy * W + ix];
            tf[gy * 68 + gx] = u;
        }
    }
    __syncthreads();

    // Thread's 6x6 neighborhood: tile rows 2ty..2ty+5, float cols 2tx..2tx+5
    // = float2 cols tx..tx+2 (8B-aligned ds_read_b64 x3 per row).
    float v[6][6];
    const int r0 = 2 * ty;
#pragma unroll
    for (int r = 0; r < 6; ++r) {
        const float2 q0 = tile[r0 + r][tx];
        const float2 q1 = tile[r0 + r][tx + 1];
        const float2 q2 = tile[r0 + r][tx + 2];
        v[r][0] = q0.x; v[r][1] = q0.y; v[r][2] = q1.x;
        v[r][3] = q1.y; v[r][4] = q2.x; v[r][5] = q2.y;
    }

    // Shared 4x4 core: v[1..4][1..4] -> sorted; keep mids a[3..12] (=S10).
    // Drops legal: n=25,k=13 run16>=14; n=23,k=12 run14>=13; n=21,k=11 run12>=12.
    float a[16];
#pragma unroll
    for (int r = 0; r < 4; ++r)
#pragma unroll
        for (int c = 0; c < 4; ++c)
            a[r * 4 + c] = v[r + 1][c + 1];
    oesort<0, 16>(a);
    const float* S = &a[3];                // S[0..9] sorted, n=19, k=10

    // Shared edge runs (each used by 2 windows).
    float rT[4] = { v[0][1], v[0][2], v[0][3], v[0][4] };
    float rB[4] = { v[5][1], v[5][2], v[5][3], v[5][4] };
    float cL[4] = { v[1][0], v[2][0], v[3][0], v[4][0] };
    float cR[4] = { v[1][5], v[2][5], v[3][5], v[4][5] };
    oesort<0, 4>(rT); oesort<0, 4>(rB); oesort<0, 4>(cL); oesort<0, 4>(cR);

    float med[2][2];
#pragma unroll
    for (int wy = 0; wy < 2; ++wy) {
#pragma unroll
        for (int wx = 0; wx < 2; ++wx) {
            const float* rowr = wy ? rB : rT;
            const float* colr = wx ? cR : cL;
            float M[8];
#pragma unroll
            for (int i = 0; i < 4; ++i) { M[i] = rowr[i]; M[4 + i] = colr[i]; }
            oemerge<0, 8, 1>(M);           // merge two sorted 4s -> sorted 8
            const float c = v[wy ? 5 : 0][wx ? 5 : 0];

            // k=10 of S10 u M8 u {c}: comps (i,j,m), i+j+m=10.
            float cand[18];
            cand[0] = S[9];                              // m=0, j=0
#pragma unroll
            for (int j = 1; j <= 8; ++j)                 // m=0: i=10-j
                cand[j] = fmaxf(S[9 - j], M[j - 1]);
            cand[9] = fmaxf(S[8], c);                    // m=1, j=0
#pragma unroll
            for (int j = 1; j <= 8; ++j)                 // m=1: i=9-j
                cand[9 + j] = fmaxf(fmaxf(S[8 - j], M[j - 1]), c);

            const float t0 = min3f(cand[0],  cand[1],  cand[2]);
            const float t1 = min3f(cand[3],  cand[4],  cand[5]);
            const float t2 = min3f(cand[6],  cand[7],  cand[8]);
            const float t3 = min3f(cand[9],  cand[10], cand[11]);
            const float t4 = min3f(cand[12], cand[13], cand[14]);
            const float t5 = min3f(cand[15], cand[16], cand[17]);
            med[wy][wx] = fminf(min3f(t0, t1, t2), min3f(t3, t4, t5));
        }
    }

    const int ox = blockIdx.x * 64 + 2 * tx;
    const int oy = blockIdx.y * 16 + r0;
    float* op = out + (size_t)ch * H * W + (size_t)oy * W + ox;
    *reinterpret_cast<float2*>(op)     = make_float2(med[0][0], med[0][1]);
    *reinterpret_cast<float2*>(op + W) = make_float2(med[1][0], med[1][1]);
}

extern "C" void kernel_launch(void* const* d_in, const int* in_sizes, int n_in,
                              void* d_out, int out_size, void* d_ws, size_t ws_size,
                              hipStream_t stream) {
    const float* x = (const float*)d_in[0];
    float* out = (float*)d_out;
    const int H = 1024, W = 1024;
    const int nch = in_sizes[0] / (H * W);   // B*C = 12

    dim3 block(32, 8, 1);
    dim3 grid(W / 64, H / 16, nch);
    median5x5_kernel<<<grid, block, 0, stream>>>(x, out, H, W);
}